// Round 1
// baseline (1275.540 us; speedup 1.0000x reference)
//
#include <hip/hip_runtime.h>
#include <math.h>

typedef unsigned short u16;
typedef __bf16 bf16x8 __attribute__((ext_vector_type(8)));
typedef float f32x4 __attribute__((ext_vector_type(4)));

#define T_TOK 4096
#define DIM   1024
#define HID   4096
#define NE    8
#define TOPK  3
#define NPAIR 12288   // T_TOK * TOPK, always exact

// ---------------- ws layout (bytes) ----------------
// ctrl ints: [0..7]=ecnt, [8..15]=eoff, [16..23]=efill
constexpr size_t OFF_CTRL = 0;
constexpr size_t OFF_XB   = 256;                                   // 4096*1024*2      = 8,388,608
constexpr size_t OFF_W12T = OFF_XB   + (size_t)T_TOK * DIM * 2;    // 8*8192*1024*2    = 134,217,728
constexpr size_t OFF_W3T  = OFF_W12T + (size_t)NE * 2 * HID * DIM * 2; // 8*1024*4096*2 = 67,108,864
constexpr size_t OFF_HID  = OFF_W3T  + (size_t)NE * DIM * HID * 2; // 12288*4096*2     = 100,663,296
constexpr size_t OFF_Y    = OFF_HID  + (size_t)NPAIR * HID * 2;    // 12288*1024*4     = 50,331,648
constexpr size_t OFF_PTOK = OFF_Y    + (size_t)NPAIR * DIM * 4;    // 12288*4
constexpr size_t OFF_TE   = OFF_PTOK + (size_t)NPAIR * 4;          // 4096*3*4
constexpr size_t OFF_TW   = OFF_TE   + (size_t)T_TOK * TOPK * 4;
constexpr size_t OFF_TS   = OFF_TW   + (size_t)T_TOK * TOPK * 4;
// total ~361 MB

__device__ __forceinline__ u16 f2bf(float f) {
    unsigned u = __builtin_bit_cast(unsigned, f);
    u += 0x7fffu + ((u >> 16) & 1u);   // RNE
    return (u16)(u >> 16);
}

// ---------------- conversion kernels ----------------
__global__ __launch_bounds__(256) void cast_x_kernel(const float4* __restrict__ in,
                                                     uint2* __restrict__ out, int n4) {
    int i = blockIdx.x * blockDim.x + threadIdx.x;
    if (i >= n4) return;
    float4 f = in[i];
    uint2 v;
    v.x = (unsigned)f2bf(f.x) | ((unsigned)f2bf(f.y) << 16);
    v.y = (unsigned)f2bf(f.z) | ((unsigned)f2bf(f.w) << 16);
    out[i] = v;
}

// in: [E][K][N] fp32  ->  out: [E][N][K] bf16
__global__ __launch_bounds__(256) void transpose_cast_kernel(const float* __restrict__ in,
                                                             u16* __restrict__ out, int K, int N) {
    __shared__ float tile[32][33];
    const float* inp = in + (size_t)blockIdx.z * K * N;
    u16* outp = out + (size_t)blockIdx.z * K * N;
    const int n0 = blockIdx.x * 32, k0 = blockIdx.y * 32;
    const int tx = threadIdx.x & 31, ty = threadIdx.x >> 5;
#pragma unroll
    for (int i = 0; i < 4; i++) {
        int k = ty + i * 8;
        tile[k][tx] = inp[(size_t)(k0 + k) * N + (n0 + tx)];
    }
    __syncthreads();
    const int row = threadIdx.x >> 3;         // 0..31 (n within tile)
    const int kq = (threadIdx.x & 7) * 4;     // 0..28 (k within tile)
    unsigned lo = (unsigned)f2bf(tile[kq + 0][row]) | ((unsigned)f2bf(tile[kq + 1][row]) << 16);
    unsigned hi = (unsigned)f2bf(tile[kq + 2][row]) | ((unsigned)f2bf(tile[kq + 3][row]) << 16);
    uint2 v; v.x = lo; v.y = hi;
    *(uint2*)(&outp[(size_t)(n0 + row) * K + (k0 + kq)]) = v;
}

// ---------------- router ----------------
__global__ __launch_bounds__(64) void router_kernel(const float* __restrict__ x,
                                                    const float* __restrict__ rw,
                                                    const float* __restrict__ rb,
                                                    int* __restrict__ tok_expert,
                                                    float* __restrict__ tok_w,
                                                    int* __restrict__ ctrl,
                                                    float* __restrict__ aux) {
    const int t = blockIdx.x, lane = threadIdx.x;
    const float* xr = x + (size_t)t * DIM;
    float p[NE];
#pragma unroll
    for (int e = 0; e < NE; e++) p[e] = 0.f;
    for (int d = lane; d < DIM; d += 64) {
        float xv = xr[d];
#pragma unroll
        for (int e = 0; e < NE; e++) p[e] += xv * rw[e * DIM + d];
    }
#pragma unroll
    for (int e = 0; e < NE; e++) {
#pragma unroll
        for (int off = 32; off; off >>= 1) p[e] += __shfl_down(p[e], off, 64);
    }
    if (lane == 0) {
        float s[NE]; float auxs = 0.f;
#pragma unroll
        for (int e = 0; e < NE; e++) {
            float lg = p[e] + rb[e];
            auxs += lg * lg;
            s[e] = 1.f / (1.f + expf(-lg));
        }
        atomicAdd(aux, auxs * (0.01f / 32768.0f));
        unsigned mask = 0; float wsum = 0.f;
        int idxs[TOPK]; float vals[TOPK];
        for (int k = 0; k < TOPK; k++) {
            float best = -1.f; int bi = 0;
            for (int e = 0; e < NE; e++)
                if (!((mask >> e) & 1u) && s[e] > best) { best = s[e]; bi = e; }
            mask |= 1u << bi; idxs[k] = bi; vals[k] = best; wsum += best;
        }
        wsum += 1e-6f;
        for (int k = 0; k < TOPK; k++) {
            tok_expert[t * TOPK + k] = idxs[k];
            tok_w[t * TOPK + k] = vals[k] / wsum;
            atomicAdd(&ctrl[idxs[k]], 1);
        }
    }
}

__global__ void scan_kernel(int* __restrict__ ctrl) {
    if (threadIdx.x == 0) {
        int acc = 0;
        for (int e = 0; e < NE; e++) { ctrl[8 + e] = acc; acc += ctrl[e]; }
    }
}

__global__ __launch_bounds__(256) void assign_kernel(const int* __restrict__ tok_expert,
                                                     const float* __restrict__ tok_w,
                                                     int* __restrict__ ctrl,
                                                     int* __restrict__ pair_token,
                                                     int* __restrict__ tok_slot) {
    int t = blockIdx.x * blockDim.x + threadIdx.x;
    if (t >= T_TOK) return;
    for (int k = 0; k < TOPK; k++) {
        int e = tok_expert[t * TOPK + k];
        int pos = atomicAdd(&ctrl[16 + e], 1);
        int slot = ctrl[8 + e] + pos;
        pair_token[slot] = t;
        tok_slot[t * TOPK + k] = slot;
    }
}

// ---------------- GEMM1: hidden = silu(x@w1)*(x@w2), gathered rows ----------------
// tiles: BM=128 rows, BN=64 cols per half, BK=32; 256 thr = 4 waves (2x2)
#define LDST 40   // LDS row stride in bf16 (32 + 8 pad -> 2-way bank conflicts only)

__global__ __launch_bounds__(256) void gemm1_kernel(const u16* __restrict__ xb,
                                                    const u16* __restrict__ w12t,
                                                    const int* __restrict__ pair_token,
                                                    const int* __restrict__ ctrl,
                                                    u16* __restrict__ hidden) {
    const int e = blockIdx.z;
    const int cnt = ctrl[e];
    if ((int)blockIdx.y * 128 >= cnt) return;
    const int off = ctrl[8 + e];
    const int rowbase = off + blockIdx.y * 128;
    const int rowend = off + cnt;
    const int n0 = blockIdx.x * 64;

    __shared__ __align__(16) u16 Alds[128 * LDST];
    __shared__ __align__(16) u16 Blds[2][64 * LDST];

    const int tid = threadIdx.x;
    const int ar0 = tid >> 2;            // 0..63
    const int ar1 = ar0 + 64;            // 64..127
    const int aq = (tid & 3) * 8;        // 16B chunk within 32-wide k-slab
    const int sr0 = rowbase + ar0, sr1 = rowbase + ar1;
    const int t0 = (sr0 < rowend) ? pair_token[sr0] : 0;
    const int t1 = (sr1 < rowend) ? pair_token[sr1] : 0;
    const u16* asrc0 = xb + (size_t)t0 * DIM + aq;
    const u16* asrc1 = xb + (size_t)t1 * DIM + aq;
    const u16* bsrc0 = w12t + (size_t)e * (2 * HID) * DIM + (size_t)(n0 + ar0) * DIM + aq;
    const u16* bsrc1 = bsrc0 + (size_t)HID * DIM;
    u16* adst0 = Alds + ar0 * LDST + aq;
    u16* adst1 = Alds + ar1 * LDST + aq;
    u16* bdst0 = Blds[0] + ar0 * LDST + aq;
    u16* bdst1 = Blds[1] + ar0 * LDST + aq;

    const int wave = tid >> 6, lane = tid & 63;
    const int wm = wave >> 1, wn = wave & 1;
    const int lrow = lane & 15, lq = lane >> 4;
    const u16* Afrag  = Alds + (wm * 64 + lrow) * LDST + lq * 8;
    const u16* B0frag = Blds[0] + (wn * 32 + lrow) * LDST + lq * 8;
    const u16* B1frag = Blds[1] + (wn * 32 + lrow) * LDST + lq * 8;

    f32x4 acc0[4][2], acc1[4][2];
#pragma unroll
    for (int mf = 0; mf < 4; mf++)
#pragma unroll
        for (int nf = 0; nf < 2; nf++) { acc0[mf][nf] = (f32x4)0.f; acc1[mf][nf] = (f32x4)0.f; }

    for (int k0 = 0; k0 < DIM; k0 += 32) {
        *(uint4*)adst0 = *(const uint4*)(asrc0 + k0);
        *(uint4*)adst1 = *(const uint4*)(asrc1 + k0);
        *(uint4*)bdst0 = *(const uint4*)(bsrc0 + k0);
        *(uint4*)bdst1 = *(const uint4*)(bsrc1 + k0);
        __syncthreads();
        bf16x8 a[4], b0[2], b1[2];
#pragma unroll
        for (int mf = 0; mf < 4; mf++) a[mf] = *(const bf16x8*)(Afrag + mf * 16 * LDST);
#pragma unroll
        for (int nf = 0; nf < 2; nf++) {
            b0[nf] = *(const bf16x8*)(B0frag + nf * 16 * LDST);
            b1[nf] = *(const bf16x8*)(B1frag + nf * 16 * LDST);
        }
#pragma unroll
        for (int mf = 0; mf < 4; mf++)
#pragma unroll
            for (int nf = 0; nf < 2; nf++) {
                acc0[mf][nf] = __builtin_amdgcn_mfma_f32_16x16x32_bf16(a[mf], b0[nf], acc0[mf][nf], 0, 0, 0);
                acc1[mf][nf] = __builtin_amdgcn_mfma_f32_16x16x32_bf16(a[mf], b1[nf], acc1[mf][nf], 0, 0, 0);
            }
        __syncthreads();
    }
    // epilogue: C/D layout col=lane&15, row=(lane>>4)*4+reg
#pragma unroll
    for (int mf = 0; mf < 4; mf++)
#pragma unroll
        for (int nf = 0; nf < 2; nf++) {
            const int gc = n0 + wn * 32 + nf * 16 + lrow;
#pragma unroll
            for (int r = 0; r < 4; r++) {
                const int gr = rowbase + wm * 64 + mf * 16 + lq * 4 + r;
                if (gr < rowend) {
                    float x1 = acc0[mf][nf][r], x2 = acc1[mf][nf][r];
                    float h = x1 / (1.f + __expf(-x1)) * x2;
                    hidden[(size_t)gr * HID + gc] = f2bf(h);
                }
            }
        }
}

// ---------------- GEMM2: y = hidden @ w3 ----------------
__global__ __launch_bounds__(256) void gemm2_kernel(const u16* __restrict__ hidden,
                                                    const u16* __restrict__ w3t,
                                                    const int* __restrict__ ctrl,
                                                    float* __restrict__ ybuf) {
    const int e = blockIdx.z;
    const int cnt = ctrl[e];
    if ((int)blockIdx.y * 128 >= cnt) return;
    const int off = ctrl[8 + e];
    const int rowbase = off + blockIdx.y * 128;
    const int rowend = off + cnt;
    const int n0 = blockIdx.x * 64;

    __shared__ __align__(16) u16 Alds[128 * LDST];
    __shared__ __align__(16) u16 Blds[64 * LDST];

    const int tid = threadIdx.x;
    const int ar0 = tid >> 2;
    const int ar1 = ar0 + 64;
    const int aq = (tid & 3) * 8;
    const int sr0 = min(rowbase + ar0, NPAIR - 1);
    const int sr1 = min(rowbase + ar1, NPAIR - 1);
    const u16* asrc0 = hidden + (size_t)sr0 * HID + aq;
    const u16* asrc1 = hidden + (size_t)sr1 * HID + aq;
    const u16* bsrc = w3t + (size_t)e * DIM * HID + (size_t)(n0 + ar0) * HID + aq;
    u16* adst0 = Alds + ar0 * LDST + aq;
    u16* adst1 = Alds + ar1 * LDST + aq;
    u16* bdst = Blds + ar0 * LDST + aq;

    const int wave = tid >> 6, lane = tid & 63;
    const int wm = wave >> 1, wn = wave & 1;
    const int lrow = lane & 15, lq = lane >> 4;
    const u16* Afrag = Alds + (wm * 64 + lrow) * LDST + lq * 8;
    const u16* Bfrag = Blds + (wn * 32 + lrow) * LDST + lq * 8;

    f32x4 acc[4][2];
#pragma unroll
    for (int mf = 0; mf < 4; mf++)
#pragma unroll
        for (int nf = 0; nf < 2; nf++) acc[mf][nf] = (f32x4)0.f;

    for (int k0 = 0; k0 < HID; k0 += 32) {
        *(uint4*)adst0 = *(const uint4*)(asrc0 + k0);
        *(uint4*)adst1 = *(const uint4*)(asrc1 + k0);
        *(uint4*)bdst = *(const uint4*)(bsrc + k0);
        __syncthreads();
        bf16x8 a[4], b[2];
#pragma unroll
        for (int mf = 0; mf < 4; mf++) a[mf] = *(const bf16x8*)(Afrag + mf * 16 * LDST);
#pragma unroll
        for (int nf = 0; nf < 2; nf++) b[nf] = *(const bf16x8*)(Bfrag + nf * 16 * LDST);
#pragma unroll
        for (int mf = 0; mf < 4; mf++)
#pragma unroll
            for (int nf = 0; nf < 2; nf++)
                acc[mf][nf] = __builtin_amdgcn_mfma_f32_16x16x32_bf16(a[mf], b[nf], acc[mf][nf], 0, 0, 0);
        __syncthreads();
    }
#pragma unroll
    for (int mf = 0; mf < 4; mf++)
#pragma unroll
        for (int nf = 0; nf < 2; nf++) {
            const int gc = n0 + wn * 32 + nf * 16 + lrow;
#pragma unroll
            for (int r = 0; r < 4; r++) {
                const int gr = rowbase + wm * 64 + mf * 16 + lq * 4 + r;
                if (gr < rowend) ybuf[(size_t)gr * DIM + gc] = acc[mf][nf][r];
            }
        }
}

// ---------------- combine: out[t] = sum_k w_k * y[slot_k] ----------------
__global__ __launch_bounds__(256) void combine_kernel(const float* __restrict__ ybuf,
                                                      const int* __restrict__ tok_slot,
                                                      const float* __restrict__ tok_w,
                                                      float* __restrict__ out) {
    const int t = blockIdx.x;
    const int d = threadIdx.x * 4;
    const int s0 = tok_slot[t * 3 + 0], s1 = tok_slot[t * 3 + 1], s2 = tok_slot[t * 3 + 2];
    const float w0 = tok_w[t * 3 + 0], w1 = tok_w[t * 3 + 1], w2 = tok_w[t * 3 + 2];
    const float4 a0 = *(const float4*)(ybuf + (size_t)s0 * DIM + d);
    const float4 a1 = *(const float4*)(ybuf + (size_t)s1 * DIM + d);
    const float4 a2 = *(const float4*)(ybuf + (size_t)s2 * DIM + d);
    float4 o;
    o.x = w0 * a0.x + w1 * a1.x + w2 * a2.x;
    o.y = w0 * a0.y + w1 * a1.y + w2 * a2.y;
    o.z = w0 * a0.z + w1 * a1.z + w2 * a2.z;
    o.w = w0 * a0.w + w1 * a1.w + w2 * a2.w;
    *(float4*)(out + (size_t)t * DIM + d) = o;
}

extern "C" void kernel_launch(void* const* d_in, const int* in_sizes, int n_in,
                              void* d_out, int out_size, void* d_ws, size_t ws_size,
                              hipStream_t stream) {
    const float* x   = (const float*)d_in[0];
    const float* rw  = (const float*)d_in[1];
    const float* rb  = (const float*)d_in[2];
    const float* w12 = (const float*)d_in[3];
    const float* w3  = (const float*)d_in[4];
    float* out = (float*)d_out;
    char* ws = (char*)d_ws;

    int*   ctrl       = (int*)(ws + OFF_CTRL);
    u16*   xb         = (u16*)(ws + OFF_XB);
    u16*   w12t       = (u16*)(ws + OFF_W12T);
    u16*   w3t        = (u16*)(ws + OFF_W3T);
    u16*   hidden     = (u16*)(ws + OFF_HID);
    float* ybuf       = (float*)(ws + OFF_Y);
    int*   pair_token = (int*)(ws + OFF_PTOK);
    int*   tok_expert = (int*)(ws + OFF_TE);
    float* tok_w      = (float*)(ws + OFF_TW);
    int*   tok_slot   = (int*)(ws + OFF_TS);

    hipMemsetAsync(ctrl, 0, 256, stream);
    hipMemsetAsync(out + (size_t)T_TOK * DIM, 0, sizeof(float), stream);  // aux slot

    cast_x_kernel<<<4096, 256, 0, stream>>>((const float4*)x, (uint2*)xb, T_TOK * DIM / 4);
    transpose_cast_kernel<<<dim3(2 * HID / 32, DIM / 32, NE), 256, 0, stream>>>(w12, w12t, DIM, 2 * HID);
    transpose_cast_kernel<<<dim3(DIM / 32, HID / 32, NE), 256, 0, stream>>>(w3, w3t, HID, DIM);

    router_kernel<<<T_TOK, 64, 0, stream>>>(x, rw, rb, tok_expert, tok_w, ctrl,
                                            out + (size_t)T_TOK * DIM);
    scan_kernel<<<1, 64, 0, stream>>>(ctrl);
    assign_kernel<<<16, 256, 0, stream>>>(tok_expert, tok_w, ctrl, pair_token, tok_slot);

    gemm1_kernel<<<dim3(HID / 64, 32, NE), 256, 0, stream>>>(xb, w12t, pair_token, ctrl, hidden);
    gemm2_kernel<<<dim3(DIM / 64, 32, NE), 256, 0, stream>>>(hidden, w3t, ctrl, ybuf);
    combine_kernel<<<T_TOK, 256, 0, stream>>>(ybuf, tok_slot, tok_w, out);
    (void)in_sizes; (void)n_in; (void)out_size; (void)ws_size;
}

// Round 2
// 1161.998 us; speedup vs baseline: 1.0977x; 1.0977x over previous
//
#include <hip/hip_runtime.h>
#include <math.h>

typedef unsigned short u16;
typedef __bf16 bf16x8 __attribute__((ext_vector_type(8)));
typedef float f32x4 __attribute__((ext_vector_type(4)));

#define T_TOK 4096
#define DIM   1024
#define HID   4096
#define NE    8
#define TOPK  3
#define NPAIR 12288   // T_TOK * TOPK

// ---------------- ws layout (bytes) ----------------
// ctrl ints: [0..7]=ecnt, [8..15]=eoff, [16..23]=efill
constexpr size_t OFF_CTRL = 0;
constexpr size_t OFF_XB   = 256;
constexpr size_t OFF_W12T = OFF_XB   + (size_t)T_TOK * DIM * 2;
constexpr size_t OFF_W3T  = OFF_W12T + (size_t)NE * 2 * HID * DIM * 2;
constexpr size_t OFF_HID  = OFF_W3T  + (size_t)NE * DIM * HID * 2;
constexpr size_t OFF_Y    = OFF_HID  + (size_t)NPAIR * HID * 2;
constexpr size_t OFF_PTOK = OFF_Y    + (size_t)NPAIR * DIM * 4;
constexpr size_t OFF_TE   = OFF_PTOK + (size_t)NPAIR * 4;
constexpr size_t OFF_TW   = OFF_TE   + (size_t)T_TOK * TOPK * 4;
constexpr size_t OFF_TS   = OFF_TW   + (size_t)T_TOK * TOPK * 4;

__device__ __forceinline__ u16 f2bf(float f) {
    unsigned u = __builtin_bit_cast(unsigned, f);
    u += 0x7fffu + ((u >> 16) & 1u);   // RNE
    return (u16)(u >> 16);
}

// async global->LDS DMA, 16B per lane; LDS dst = wave-uniform base + lane*16
__device__ __forceinline__ void ld_g2l(const u16* g, u16* l) {
    __builtin_amdgcn_global_load_lds((__attribute__((address_space(1))) unsigned*)(g),
                                     (__attribute__((address_space(3))) unsigned*)(l),
                                     16, 0, 0);
}

// ---------------- conversion kernels ----------------
__global__ __launch_bounds__(256) void cast_x_kernel(const float4* __restrict__ in,
                                                     uint2* __restrict__ out, int n4) {
    int i = blockIdx.x * blockDim.x + threadIdx.x;
    if (i >= n4) return;
    float4 f = in[i];
    uint2 v;
    v.x = (unsigned)f2bf(f.x) | ((unsigned)f2bf(f.y) << 16);
    v.y = (unsigned)f2bf(f.z) | ((unsigned)f2bf(f.w) << 16);
    out[i] = v;
}

// in: [E][K][N] fp32  ->  out: [E][N][K] bf16.  Tile: 32 (K) x 64 (N).
__global__ __launch_bounds__(256) void transpose_cast_kernel(const float* __restrict__ in,
                                                             u16* __restrict__ out, int K, int N) {
    __shared__ float tile[32][65];
    const float* inp = in + (size_t)blockIdx.z * K * N;
    u16* outp = out + (size_t)blockIdx.z * K * N;
    const int n0 = blockIdx.x * 64, k0 = blockIdx.y * 32;
#pragma unroll
    for (int i = 0; i < 2; ++i) {
        int idx = threadIdx.x + i * 256;           // 0..511 -> 32 rows x 16 float4
        int k = idx >> 4, n4 = (idx & 15) * 4;
        float4 f = *(const float4*)(inp + (size_t)(k0 + k) * N + n0 + n4);
        tile[k][n4 + 0] = f.x; tile[k][n4 + 1] = f.y;
        tile[k][n4 + 2] = f.z; tile[k][n4 + 3] = f.w;
    }
    __syncthreads();
    const int n = threadIdx.x >> 2, c = (threadIdx.x & 3) * 8;
    u16 buf[8];
#pragma unroll
    for (int j = 0; j < 8; ++j) buf[j] = f2bf(tile[c + j][n]);
    *(uint4*)(outp + (size_t)(n0 + n) * K + k0 + c) = *(uint4*)buf;
}

// ---------------- router ----------------
__global__ __launch_bounds__(64) void router_kernel(const float* __restrict__ x,
                                                    const float* __restrict__ rw,
                                                    const float* __restrict__ rb,
                                                    int* __restrict__ tok_expert,
                                                    float* __restrict__ tok_w,
                                                    int* __restrict__ ctrl,
                                                    float* __restrict__ aux) {
    const int t = blockIdx.x, lane = threadIdx.x;
    const float* xr = x + (size_t)t * DIM;
    float p[NE];
#pragma unroll
    for (int e = 0; e < NE; e++) p[e] = 0.f;
    for (int d = lane; d < DIM; d += 64) {
        float xv = xr[d];
#pragma unroll
        for (int e = 0; e < NE; e++) p[e] += xv * rw[e * DIM + d];
    }
#pragma unroll
    for (int e = 0; e < NE; e++) {
#pragma unroll
        for (int off = 32; off; off >>= 1) p[e] += __shfl_down(p[e], off, 64);
    }
    if (lane == 0) {
        float s[NE]; float auxs = 0.f;
#pragma unroll
        for (int e = 0; e < NE; e++) {
            float lg = p[e] + rb[e];
            auxs += lg * lg;
            s[e] = 1.f / (1.f + expf(-lg));
        }
        atomicAdd(aux, auxs * (0.01f / 32768.0f));
        unsigned mask = 0; float wsum = 0.f;
        int idxs[TOPK]; float vals[TOPK];
        for (int k = 0; k < TOPK; k++) {
            float best = -1.f; int bi = 0;
            for (int e = 0; e < NE; e++)
                if (!((mask >> e) & 1u) && s[e] > best) { best = s[e]; bi = e; }
            mask |= 1u << bi; idxs[k] = bi; vals[k] = best; wsum += best;
        }
        wsum += 1e-6f;
        for (int k = 0; k < TOPK; k++) {
            tok_expert[t * TOPK + k] = idxs[k];
            tok_w[t * TOPK + k] = vals[k] / wsum;
            atomicAdd(&ctrl[idxs[k]], 1);
        }
    }
}

__global__ void scan_kernel(int* __restrict__ ctrl) {
    if (threadIdx.x == 0) {
        int acc = 0;
        for (int e = 0; e < NE; e++) { ctrl[8 + e] = acc; acc += ctrl[e]; }
    }
}

__global__ __launch_bounds__(256) void assign_kernel(const int* __restrict__ tok_expert,
                                                     const float* __restrict__ tok_w,
                                                     int* __restrict__ ctrl,
                                                     int* __restrict__ pair_token,
                                                     int* __restrict__ tok_slot) {
    int t = blockIdx.x * blockDim.x + threadIdx.x;
    if (t >= T_TOK) return;
    for (int k = 0; k < TOPK; k++) {
        int e = tok_expert[t * TOPK + k];
        int pos = atomicAdd(&ctrl[16 + e], 1);
        int slot = ctrl[8 + e] + pos;
        pair_token[slot] = t;
        tok_slot[t * TOPK + k] = slot;
    }
}

// ---------------- GEMM1: hidden = silu(x@w1)*(x@w2), gathered rows ----------------
// BM=128, BN=64 per half, BK=64; 256 thr = 4 waves (2x2).
// LDS tiles unpadded (global_load_lds), XOR-swizzled 16B chunks: stored chunk s = c ^ (row&7).
__global__ __launch_bounds__(256, 3) void gemm1_kernel(const u16* __restrict__ xb,
                                                       const u16* __restrict__ w12t,
                                                       const int* __restrict__ pair_token,
                                                       const int* __restrict__ ctrl,
                                                       u16* __restrict__ hidden) {
    const int e = blockIdx.z;
    const int cnt = ctrl[e];
    if ((int)blockIdx.y * 128 >= cnt) return;
    const int off = ctrl[8 + e];
    const int rowbase = off + blockIdx.y * 128;
    const int rowend = off + cnt;
    const int n0 = blockIdx.x * 64;

    __shared__ __align__(16) u16 Alds[128 * 64];   // 16 KB
    __shared__ __align__(16) u16 B0lds[64 * 64];   //  8 KB
    __shared__ __align__(16) u16 B1lds[64 * 64];   //  8 KB

    const int tid = threadIdx.x;
    const int wave = tid >> 6, lane = tid & 63;
    const int lr8 = lane >> 3;                 // row within 8-row DMA group
    const int lc  = (lane & 7) ^ lr8;          // swizzled source chunk

    // staging source pointers (per lane), k0 = 0
    const u16* srcA[4];
    const u16* srcB0[2];
    const u16* srcB1[2];
#pragma unroll
    for (int g = 0; g < 4; ++g) {
        int sr = rowbase + wave * 32 + g * 8 + lr8;
        int tok = (sr < rowend) ? pair_token[sr] : 0;
        srcA[g] = xb + (size_t)tok * DIM + lc * 8;
    }
#pragma unroll
    for (int g = 0; g < 2; ++g) {
        int br = n0 + wave * 16 + g * 8 + lr8;
        srcB0[g] = w12t + ((size_t)e * 2 * HID + br) * DIM + lc * 8;
        srcB1[g] = srcB0[g] + (size_t)HID * DIM;
    }

    const int wm = wave >> 1, wn = wave & 1;
    const int lrow = lane & 15, lq = lane >> 4;
    const int xm = lrow & 7;

    f32x4 acc0[4][2], acc1[4][2];
#pragma unroll
    for (int mf = 0; mf < 4; mf++)
#pragma unroll
        for (int nf = 0; nf < 2; nf++) { acc0[mf][nf] = (f32x4)0.f; acc1[mf][nf] = (f32x4)0.f; }

    for (int kt = 0; kt < DIM / 64; ++kt) {
#pragma unroll
        for (int g = 0; g < 4; ++g)
            ld_g2l(srcA[g], Alds + (wave * 32 + g * 8) * 64);
#pragma unroll
        for (int g = 0; g < 2; ++g) {
            ld_g2l(srcB0[g], B0lds + (wave * 16 + g * 8) * 64);
            ld_g2l(srcB1[g], B1lds + (wave * 16 + g * 8) * 64);
        }
#pragma unroll
        for (int g = 0; g < 4; ++g) srcA[g] += 64;
#pragma unroll
        for (int g = 0; g < 2; ++g) { srcB0[g] += 64; srcB1[g] += 64; }
        __syncthreads();
#pragma unroll
        for (int kk = 0; kk < 2; ++kk) {
            const int so = (((kk << 2) | lq) ^ xm) * 8;
            bf16x8 a[4], b0[2], b1[2];
#pragma unroll
            for (int mf = 0; mf < 4; mf++)
                a[mf] = *(const bf16x8*)(Alds + (wm * 64 + mf * 16 + lrow) * 64 + so);
#pragma unroll
            for (int nf = 0; nf < 2; nf++) {
                b0[nf] = *(const bf16x8*)(B0lds + (wn * 32 + nf * 16 + lrow) * 64 + so);
                b1[nf] = *(const bf16x8*)(B1lds + (wn * 32 + nf * 16 + lrow) * 64 + so);
            }
#pragma unroll
            for (int mf = 0; mf < 4; mf++)
#pragma unroll
                for (int nf = 0; nf < 2; nf++) {
                    acc0[mf][nf] = __builtin_amdgcn_mfma_f32_16x16x32_bf16(a[mf], b0[nf], acc0[mf][nf], 0, 0, 0);
                    acc1[mf][nf] = __builtin_amdgcn_mfma_f32_16x16x32_bf16(a[mf], b1[nf], acc1[mf][nf], 0, 0, 0);
                }
        }
        __syncthreads();
    }
    // epilogue: C/D layout col=lane&15, row=(lane>>4)*4+reg
#pragma unroll
    for (int mf = 0; mf < 4; mf++)
#pragma unroll
        for (int nf = 0; nf < 2; nf++) {
            const int gc = n0 + wn * 32 + nf * 16 + lrow;
#pragma unroll
            for (int r = 0; r < 4; r++) {
                const int gr = rowbase + wm * 64 + mf * 16 + lq * 4 + r;
                if (gr < rowend) {
                    float x1 = acc0[mf][nf][r], x2 = acc1[mf][nf][r];
                    float h = x1 / (1.f + __expf(-x1)) * x2;
                    hidden[(size_t)gr * HID + gc] = f2bf(h);
                }
            }
        }
}

// ---------------- GEMM2: y = hidden @ w3 ----------------
// BM=128, BN=64, BK=64; same swizzled DMA staging.
__global__ __launch_bounds__(256, 3) void gemm2_kernel(const u16* __restrict__ hidden,
                                                       const u16* __restrict__ w3t,
                                                       const int* __restrict__ ctrl,
                                                       float* __restrict__ ybuf) {
    const int e = blockIdx.z;
    const int cnt = ctrl[e];
    if ((int)blockIdx.y * 128 >= cnt) return;
    const int off = ctrl[8 + e];
    const int rowbase = off + blockIdx.y * 128;
    const int rowend = off + cnt;
    const int n0 = blockIdx.x * 64;

    __shared__ __align__(16) u16 Alds[128 * 64];   // 16 KB
    __shared__ __align__(16) u16 Blds[64 * 64];    //  8 KB

    const int tid = threadIdx.x;
    const int wave = tid >> 6, lane = tid & 63;
    const int lr8 = lane >> 3;
    const int lc  = (lane & 7) ^ lr8;

    const u16* srcA[4];
    const u16* srcB[2];
#pragma unroll
    for (int g = 0; g < 4; ++g) {
        int sr = rowbase + wave * 32 + g * 8 + lr8;
        if (sr > NPAIR - 1) sr = NPAIR - 1;
        srcA[g] = hidden + (size_t)sr * HID + lc * 8;
    }
#pragma unroll
    for (int g = 0; g < 2; ++g) {
        int br = n0 + wave * 16 + g * 8 + lr8;
        srcB[g] = w3t + ((size_t)e * DIM + br) * HID + lc * 8;
    }

    const int wm = wave >> 1, wn = wave & 1;
    const int lrow = lane & 15, lq = lane >> 4;
    const int xm = lrow & 7;

    f32x4 acc[4][2];
#pragma unroll
    for (int mf = 0; mf < 4; mf++)
#pragma unroll
        for (int nf = 0; nf < 2; nf++) acc[mf][nf] = (f32x4)0.f;

    for (int kt = 0; kt < HID / 64; ++kt) {
#pragma unroll
        for (int g = 0; g < 4; ++g)
            ld_g2l(srcA[g], Alds + (wave * 32 + g * 8) * 64);
#pragma unroll
        for (int g = 0; g < 2; ++g)
            ld_g2l(srcB[g], Blds + (wave * 16 + g * 8) * 64);
#pragma unroll
        for (int g = 0; g < 4; ++g) srcA[g] += 64;
#pragma unroll
        for (int g = 0; g < 2; ++g) srcB[g] += 64;
        __syncthreads();
#pragma unroll
        for (int kk = 0; kk < 2; ++kk) {
            const int so = (((kk << 2) | lq) ^ xm) * 8;
            bf16x8 a[4], b[2];
#pragma unroll
            for (int mf = 0; mf < 4; mf++)
                a[mf] = *(const bf16x8*)(Alds + (wm * 64 + mf * 16 + lrow) * 64 + so);
#pragma unroll
            for (int nf = 0; nf < 2; nf++)
                b[nf] = *(const bf16x8*)(Blds + (wn * 32 + nf * 16 + lrow) * 64 + so);
#pragma unroll
            for (int mf = 0; mf < 4; mf++)
#pragma unroll
                for (int nf = 0; nf < 2; nf++)
                    acc[mf][nf] = __builtin_amdgcn_mfma_f32_16x16x32_bf16(a[mf], b[nf], acc[mf][nf], 0, 0, 0);
        }
        __syncthreads();
    }
#pragma unroll
    for (int mf = 0; mf < 4; mf++)
#pragma unroll
        for (int nf = 0; nf < 2; nf++) {
            const int gc = n0 + wn * 32 + nf * 16 + lrow;
#pragma unroll
            for (int r = 0; r < 4; r++) {
                const int gr = rowbase + wm * 64 + mf * 16 + lq * 4 + r;
                if (gr < rowend) ybuf[(size_t)gr * DIM + gc] = acc[mf][nf][r];
            }
        }
}

// ---------------- combine: out[t] = sum_k w_k * y[slot_k] ----------------
__global__ __launch_bounds__(256) void combine_kernel(const float* __restrict__ ybuf,
                                                      const int* __restrict__ tok_slot,
                                                      const float* __restrict__ tok_w,
                                                      float* __restrict__ out) {
    const int t = blockIdx.x;
    const int d = threadIdx.x * 4;
    const int s0 = tok_slot[t * 3 + 0], s1 = tok_slot[t * 3 + 1], s2 = tok_slot[t * 3 + 2];
    const float w0 = tok_w[t * 3 + 0], w1 = tok_w[t * 3 + 1], w2 = tok_w[t * 3 + 2];
    const float4 a0 = *(const float4*)(ybuf + (size_t)s0 * DIM + d);
    const float4 a1 = *(const float4*)(ybuf + (size_t)s1 * DIM + d);
    const float4 a2 = *(const float4*)(ybuf + (size_t)s2 * DIM + d);
    float4 o;
    o.x = w0 * a0.x + w1 * a1.x + w2 * a2.x;
    o.y = w0 * a0.y + w1 * a1.y + w2 * a2.y;
    o.z = w0 * a0.z + w1 * a1.z + w2 * a2.z;
    o.w = w0 * a0.w + w1 * a1.w + w2 * a2.w;
    *(float4*)(out + (size_t)t * DIM + d) = o;
}

extern "C" void kernel_launch(void* const* d_in, const int* in_sizes, int n_in,
                              void* d_out, int out_size, void* d_ws, size_t ws_size,
                              hipStream_t stream) {
    const float* x   = (const float*)d_in[0];
    const float* rw  = (const float*)d_in[1];
    const float* rb  = (const float*)d_in[2];
    const float* w12 = (const float*)d_in[3];
    const float* w3  = (const float*)d_in[4];
    float* out = (float*)d_out;
    char* ws = (char*)d_ws;

    int*   ctrl       = (int*)(ws + OFF_CTRL);
    u16*   xb         = (u16*)(ws + OFF_XB);
    u16*   w12t       = (u16*)(ws + OFF_W12T);
    u16*   w3t        = (u16*)(ws + OFF_W3T);
    u16*   hidden     = (u16*)(ws + OFF_HID);
    float* ybuf       = (float*)(ws + OFF_Y);
    int*   pair_token = (int*)(ws + OFF_PTOK);
    int*   tok_expert = (int*)(ws + OFF_TE);
    float* tok_w      = (float*)(ws + OFF_TW);
    int*   tok_slot   = (int*)(ws + OFF_TS);

    hipMemsetAsync(ctrl, 0, 256, stream);
    hipMemsetAsync(out + (size_t)T_TOK * DIM, 0, sizeof(float), stream);  // aux slot

    cast_x_kernel<<<4096, 256, 0, stream>>>((const float4*)x, (uint2*)xb, T_TOK * DIM / 4);
    transpose_cast_kernel<<<dim3(2 * HID / 64, DIM / 32, NE), 256, 0, stream>>>(w12, w12t, DIM, 2 * HID);
    transpose_cast_kernel<<<dim3(DIM / 64, HID / 32, NE), 256, 0, stream>>>(w3, w3t, HID, DIM);

    router_kernel<<<T_TOK, 64, 0, stream>>>(x, rw, rb, tok_expert, tok_w, ctrl,
                                            out + (size_t)T_TOK * DIM);
    scan_kernel<<<1, 64, 0, stream>>>(ctrl);
    assign_kernel<<<16, 256, 0, stream>>>(tok_expert, tok_w, ctrl, pair_token, tok_slot);

    gemm1_kernel<<<dim3(HID / 64, 32, NE), 256, 0, stream>>>(xb, w12t, pair_token, ctrl, hidden);
    gemm2_kernel<<<dim3(DIM / 64, 32, NE), 256, 0, stream>>>(hidden, w3t, ctrl, ybuf);
    combine_kernel<<<T_TOK, 256, 0, stream>>>(ybuf, tok_slot, tok_w, out);
    (void)in_sizes; (void)n_in; (void)out_size; (void)ws_size;
}

// Round 3
// 987.269 us; speedup vs baseline: 1.2920x; 1.1770x over previous
//
#include <hip/hip_runtime.h>
#include <math.h>

typedef unsigned short u16;
typedef __bf16 bf16x8 __attribute__((ext_vector_type(8)));
typedef float f32x4 __attribute__((ext_vector_type(4)));

#define T_TOK 4096
#define DIM   1024
#define HID   4096
#define NE    8
#define TOPK  3
#define NPAIR 12288   // T_TOK * TOPK

// ---------------- ws layout (bytes) ----------------
// ctrl ints: [0..7]=ecnt, [8..15]=eoff, [16..23]=efill
constexpr size_t OFF_CTRL = 0;
constexpr size_t OFF_XB   = 256;
constexpr size_t OFF_W12T = OFF_XB   + (size_t)T_TOK * DIM * 2;
constexpr size_t OFF_W3T  = OFF_W12T + (size_t)NE * 2 * HID * DIM * 2;
constexpr size_t OFF_HID  = OFF_W3T  + (size_t)NE * DIM * HID * 2;
constexpr size_t OFF_Y    = OFF_HID  + (size_t)NPAIR * HID * 2;
constexpr size_t OFF_PTOK = OFF_Y    + (size_t)NPAIR * DIM * 4;
constexpr size_t OFF_TE   = OFF_PTOK + (size_t)NPAIR * 4;
constexpr size_t OFF_TW   = OFF_TE   + (size_t)T_TOK * TOPK * 4;
constexpr size_t OFF_TS   = OFF_TW   + (size_t)T_TOK * TOPK * 4;

__device__ __forceinline__ u16 f2bf(float f) {
    unsigned u = __builtin_bit_cast(unsigned, f);
    u += 0x7fffu + ((u >> 16) & 1u);   // RNE
    return (u16)(u >> 16);
}

// async global->LDS DMA, 16B per lane; LDS dst = wave-uniform base + lane*16
__device__ __forceinline__ void ld_g2l(const u16* g, u16* l) {
    __builtin_amdgcn_global_load_lds((__attribute__((address_space(1))) unsigned*)(g),
                                     (__attribute__((address_space(3))) unsigned*)(l),
                                     16, 0, 0);
}

// ---------------- transpose-cast: [E][K][N] fp32 -> [E][N][K] bf16 ----------------
// Tile: 64 (K) x 32 (N). Reads 128 B per row; writes 128 B contiguous per out-row.
__global__ __launch_bounds__(256) void transpose_cast_kernel(const float* __restrict__ in,
                                                             u16* __restrict__ out, int K, int N) {
    __shared__ float tile[64][33];
    const float* inp = in + (size_t)blockIdx.z * K * N;
    u16* outp = out + (size_t)blockIdx.z * K * N;
    const int n0 = blockIdx.x * 32, k0 = blockIdx.y * 64;
    const int tid = threadIdx.x;
#pragma unroll
    for (int i = 0; i < 2; ++i) {
        int k = i * 32 + (tid >> 3);
        int c4 = (tid & 7) * 4;
        float4 f = *(const float4*)(inp + (size_t)(k0 + k) * N + n0 + c4);
        tile[k][c4 + 0] = f.x; tile[k][c4 + 1] = f.y;
        tile[k][c4 + 2] = f.z; tile[k][c4 + 3] = f.w;
    }
    __syncthreads();
    const int n = tid >> 3, c = (tid & 7) * 8;
    u16 buf[8];
#pragma unroll
    for (int j = 0; j < 8; ++j) buf[j] = f2bf(tile[c + j][n]);
    *(uint4*)(outp + (size_t)(n0 + n) * K + k0 + c) = *(uint4*)buf;
}

// ---------------- router (fused x->bf16 cast, block-level atomics) ----------------
// 4 tokens per 256-thread block (wave per token).
__global__ __launch_bounds__(256) void router_kernel(const float* __restrict__ x,
                                                     const float* __restrict__ rw,
                                                     const float* __restrict__ rb,
                                                     u16* __restrict__ xb,
                                                     int* __restrict__ tok_expert,
                                                     float* __restrict__ tok_w,
                                                     int* __restrict__ ctrl,
                                                     float* __restrict__ aux) {
    __shared__ int hist[NE];
    __shared__ float auxsh;
    const int tid = threadIdx.x;
    if (tid < NE) hist[tid] = 0;
    if (tid == NE) auxsh = 0.f;
    __syncthreads();

    const int wave = tid >> 6, lane = tid & 63;
    const int t = blockIdx.x * 4 + wave;
    const float* xr = x + (size_t)t * DIM;
    u16* xbr = xb + (size_t)t * DIM;

    float p[NE];
#pragma unroll
    for (int e = 0; e < NE; e++) p[e] = 0.f;
#pragma unroll
    for (int q = 0; q < 4; ++q) {
        const int d = q * 256 + lane * 4;
        float4 f = *(const float4*)(xr + d);
        uint2 v;
        v.x = (unsigned)f2bf(f.x) | ((unsigned)f2bf(f.y) << 16);
        v.y = (unsigned)f2bf(f.z) | ((unsigned)f2bf(f.w) << 16);
        *(uint2*)(xbr + d) = v;
#pragma unroll
        for (int e = 0; e < NE; e++) {
            float4 w = *(const float4*)(rw + e * DIM + d);
            p[e] += f.x * w.x + f.y * w.y + f.z * w.z + f.w * w.w;
        }
    }
#pragma unroll
    for (int e = 0; e < NE; e++) {
#pragma unroll
        for (int off = 32; off; off >>= 1) p[e] += __shfl_down(p[e], off, 64);
    }
    if (lane == 0) {
        float s[NE]; float auxs = 0.f;
#pragma unroll
        for (int e = 0; e < NE; e++) {
            float lg = p[e] + rb[e];
            auxs += lg * lg;
            s[e] = 1.f / (1.f + __expf(-lg));
        }
        atomicAdd(&auxsh, auxs);
        unsigned mask = 0; float wsum = 0.f;
        int idxs[TOPK]; float vals[TOPK];
        for (int k = 0; k < TOPK; k++) {
            float best = -1.f; int bi = 0;
            for (int e = 0; e < NE; e++)
                if (!((mask >> e) & 1u) && s[e] > best) { best = s[e]; bi = e; }
            mask |= 1u << bi; idxs[k] = bi; vals[k] = best; wsum += best;
        }
        wsum += 1e-6f;
        for (int k = 0; k < TOPK; k++) {
            tok_expert[t * TOPK + k] = idxs[k];
            tok_w[t * TOPK + k] = vals[k] / wsum;
            atomicAdd(&hist[idxs[k]], 1);
        }
    }
    __syncthreads();
    if (tid < NE) { int h = hist[tid]; if (h) atomicAdd(&ctrl[tid], h); }
    if (tid == NE) atomicAdd(aux, auxsh * (0.01f / 32768.0f));
}

__global__ void scan_kernel(int* __restrict__ ctrl) {
    if (threadIdx.x == 0) {
        int acc = 0;
        for (int e = 0; e < NE; e++) { ctrl[8 + e] = acc; acc += ctrl[e]; }
    }
}

__global__ __launch_bounds__(256) void assign_kernel(const int* __restrict__ tok_expert,
                                                     const float* __restrict__ tok_w,
                                                     int* __restrict__ ctrl,
                                                     int* __restrict__ pair_token,
                                                     int* __restrict__ tok_slot) {
    int t = blockIdx.x * blockDim.x + threadIdx.x;
    if (t >= T_TOK) return;
    for (int k = 0; k < TOPK; k++) {
        int e = tok_expert[t * TOPK + k];
        int pos = atomicAdd(&ctrl[16 + e], 1);
        int slot = ctrl[8 + e] + pos;
        pair_token[slot] = t;
        tok_slot[t * TOPK + k] = slot;
    }
}

// ---------------- GEMM1: hidden = silu(x@w1)*(x@w2), gathered rows ----------------
// BM=128, BN=64 per half (128 effective), BK=64; 4 waves (2x2); XOR-swizzled DMA staging.
__global__ __launch_bounds__(256, 3) void gemm1_kernel(const u16* __restrict__ xb,
                                                       const u16* __restrict__ w12t,
                                                       const int* __restrict__ pair_token,
                                                       const int* __restrict__ ctrl,
                                                       u16* __restrict__ hidden) {
    const int e = blockIdx.z;
    const int cnt = ctrl[e];
    if ((int)blockIdx.y * 128 >= cnt) return;
    const int off = ctrl[8 + e];
    const int rowbase = off + blockIdx.y * 128;
    const int rowend = off + cnt;
    const int n0 = blockIdx.x * 64;

    __shared__ __align__(16) u16 Alds[128 * 64];
    __shared__ __align__(16) u16 B0lds[64 * 64];
    __shared__ __align__(16) u16 B1lds[64 * 64];

    const int tid = threadIdx.x;
    const int wave = tid >> 6, lane = tid & 63;
    const int lr8 = lane >> 3;
    const int lc  = (lane & 7) ^ lr8;

    const u16* srcA[4];
    const u16* srcB0[2];
    const u16* srcB1[2];
#pragma unroll
    for (int g = 0; g < 4; ++g) {
        int sr = rowbase + wave * 32 + g * 8 + lr8;
        int tok = (sr < rowend) ? pair_token[sr] : 0;
        srcA[g] = xb + (size_t)tok * DIM + lc * 8;
    }
#pragma unroll
    for (int g = 0; g < 2; ++g) {
        int br = n0 + wave * 16 + g * 8 + lr8;
        srcB0[g] = w12t + ((size_t)e * 2 * HID + br) * DIM + lc * 8;
        srcB1[g] = srcB0[g] + (size_t)HID * DIM;
    }

    const int wm = wave >> 1, wn = wave & 1;
    const int lrow = lane & 15, lq = lane >> 4;
    const int xm = lrow & 7;

    f32x4 acc0[4][2], acc1[4][2];
#pragma unroll
    for (int mf = 0; mf < 4; mf++)
#pragma unroll
        for (int nf = 0; nf < 2; nf++) { acc0[mf][nf] = (f32x4)0.f; acc1[mf][nf] = (f32x4)0.f; }

    for (int kt = 0; kt < DIM / 64; ++kt) {
#pragma unroll
        for (int g = 0; g < 4; ++g)
            ld_g2l(srcA[g], Alds + (wave * 32 + g * 8) * 64);
#pragma unroll
        for (int g = 0; g < 2; ++g) {
            ld_g2l(srcB0[g], B0lds + (wave * 16 + g * 8) * 64);
            ld_g2l(srcB1[g], B1lds + (wave * 16 + g * 8) * 64);
        }
#pragma unroll
        for (int g = 0; g < 4; ++g) srcA[g] += 64;
#pragma unroll
        for (int g = 0; g < 2; ++g) { srcB0[g] += 64; srcB1[g] += 64; }
        __syncthreads();
#pragma unroll
        for (int kk = 0; kk < 2; ++kk) {
            const int so = (((kk << 2) | lq) ^ xm) * 8;
            bf16x8 a[4], b0[2], b1[2];
#pragma unroll
            for (int mf = 0; mf < 4; mf++)
                a[mf] = *(const bf16x8*)(Alds + (wm * 64 + mf * 16 + lrow) * 64 + so);
#pragma unroll
            for (int nf = 0; nf < 2; nf++) {
                b0[nf] = *(const bf16x8*)(B0lds + (wn * 32 + nf * 16 + lrow) * 64 + so);
                b1[nf] = *(const bf16x8*)(B1lds + (wn * 32 + nf * 16 + lrow) * 64 + so);
            }
#pragma unroll
            for (int mf = 0; mf < 4; mf++)
#pragma unroll
                for (int nf = 0; nf < 2; nf++) {
                    acc0[mf][nf] = __builtin_amdgcn_mfma_f32_16x16x32_bf16(a[mf], b0[nf], acc0[mf][nf], 0, 0, 0);
                    acc1[mf][nf] = __builtin_amdgcn_mfma_f32_16x16x32_bf16(a[mf], b1[nf], acc1[mf][nf], 0, 0, 0);
                }
        }
        __syncthreads();
    }
#pragma unroll
    for (int mf = 0; mf < 4; mf++)
#pragma unroll
        for (int nf = 0; nf < 2; nf++) {
            const int gc = n0 + wn * 32 + nf * 16 + lrow;
#pragma unroll
            for (int r = 0; r < 4; r++) {
                const int gr = rowbase + wm * 64 + mf * 16 + lq * 4 + r;
                if (gr < rowend) {
                    float x1 = acc0[mf][nf][r], x2 = acc1[mf][nf][r];
                    float h = x1 / (1.f + __expf(-x1)) * x2;
                    hidden[(size_t)gr * HID + gc] = f2bf(h);
                }
            }
        }
}

// ---------------- GEMM2: y = hidden @ w3 ----------------
// m97 shape: BM=128, BN=128, BK=64; 4 waves (2x2), each 64x64.
__global__ __launch_bounds__(256, 3) void gemm2_kernel(const u16* __restrict__ hidden,
                                                       const u16* __restrict__ w3t,
                                                       const int* __restrict__ ctrl,
                                                       float* __restrict__ ybuf) {
    const int e = blockIdx.z;
    const int cnt = ctrl[e];
    if ((int)blockIdx.y * 128 >= cnt) return;
    const int off = ctrl[8 + e];
    const int rowbase = off + blockIdx.y * 128;
    const int rowend = off + cnt;
    const int n0 = blockIdx.x * 128;

    __shared__ __align__(16) u16 Alds[128 * 64];   // 16 KB
    __shared__ __align__(16) u16 Blds[128 * 64];   // 16 KB

    const int tid = threadIdx.x;
    const int wave = tid >> 6, lane = tid & 63;
    const int lr8 = lane >> 3;
    const int lc  = (lane & 7) ^ lr8;

    const u16* srcA[4];
    const u16* srcB[4];
#pragma unroll
    for (int g = 0; g < 4; ++g) {
        int sr = rowbase + wave * 32 + g * 8 + lr8;
        if (sr > NPAIR - 1) sr = NPAIR - 1;
        srcA[g] = hidden + (size_t)sr * HID + lc * 8;
        int br = n0 + wave * 32 + g * 8 + lr8;
        srcB[g] = w3t + ((size_t)e * DIM + br) * HID + lc * 8;
    }

    const int wm = wave >> 1, wn = wave & 1;
    const int lrow = lane & 15, lq = lane >> 4;
    const int xm = lrow & 7;

    f32x4 acc[4][4];
#pragma unroll
    for (int mf = 0; mf < 4; mf++)
#pragma unroll
        for (int nf = 0; nf < 4; nf++) acc[mf][nf] = (f32x4)0.f;

    for (int kt = 0; kt < HID / 64; ++kt) {
#pragma unroll
        for (int g = 0; g < 4; ++g) {
            ld_g2l(srcA[g], Alds + (wave * 32 + g * 8) * 64);
            ld_g2l(srcB[g], Blds + (wave * 32 + g * 8) * 64);
        }
#pragma unroll
        for (int g = 0; g < 4; ++g) { srcA[g] += 64; srcB[g] += 64; }
        __syncthreads();
#pragma unroll
        for (int kk = 0; kk < 2; ++kk) {
            const int so = (((kk << 2) | lq) ^ xm) * 8;
            bf16x8 a[4], b[4];
#pragma unroll
            for (int mf = 0; mf < 4; mf++)
                a[mf] = *(const bf16x8*)(Alds + (wm * 64 + mf * 16 + lrow) * 64 + so);
#pragma unroll
            for (int nf = 0; nf < 4; nf++)
                b[nf] = *(const bf16x8*)(Blds + (wn * 64 + nf * 16 + lrow) * 64 + so);
#pragma unroll
            for (int mf = 0; mf < 4; mf++)
#pragma unroll
                for (int nf = 0; nf < 4; nf++)
                    acc[mf][nf] = __builtin_amdgcn_mfma_f32_16x16x32_bf16(a[mf], b[nf], acc[mf][nf], 0, 0, 0);
        }
        __syncthreads();
    }
#pragma unroll
    for (int mf = 0; mf < 4; mf++)
#pragma unroll
        for (int nf = 0; nf < 4; nf++) {
            const int gc = n0 + wn * 64 + nf * 16 + lrow;
#pragma unroll
            for (int r = 0; r < 4; r++) {
                const int gr = rowbase + wm * 64 + mf * 16 + lq * 4 + r;
                if (gr < rowend) ybuf[(size_t)gr * DIM + gc] = acc[mf][nf][r];
            }
        }
}

// ---------------- combine: out[t] = sum_k w_k * y[slot_k] ----------------
__global__ __launch_bounds__(256) void combine_kernel(const float* __restrict__ ybuf,
                                                      const int* __restrict__ tok_slot,
                                                      const float* __restrict__ tok_w,
                                                      float* __restrict__ out) {
    const int t = blockIdx.x;
    const int d = threadIdx.x * 4;
    const int s0 = tok_slot[t * 3 + 0], s1 = tok_slot[t * 3 + 1], s2 = tok_slot[t * 3 + 2];
    const float w0 = tok_w[t * 3 + 0], w1 = tok_w[t * 3 + 1], w2 = tok_w[t * 3 + 2];
    const float4 a0 = *(const float4*)(ybuf + (size_t)s0 * DIM + d);
    const float4 a1 = *(const float4*)(ybuf + (size_t)s1 * DIM + d);
    const float4 a2 = *(const float4*)(ybuf + (size_t)s2 * DIM + d);
    float4 o;
    o.x = w0 * a0.x + w1 * a1.x + w2 * a2.x;
    o.y = w0 * a0.y + w1 * a1.y + w2 * a2.y;
    o.z = w0 * a0.z + w1 * a1.z + w2 * a2.z;
    o.w = w0 * a0.w + w1 * a1.w + w2 * a2.w;
    *(float4*)(out + (size_t)t * DIM + d) = o;
}

extern "C" void kernel_launch(void* const* d_in, const int* in_sizes, int n_in,
                              void* d_out, int out_size, void* d_ws, size_t ws_size,
                              hipStream_t stream) {
    const float* x   = (const float*)d_in[0];
    const float* rw  = (const float*)d_in[1];
    const float* rb  = (const float*)d_in[2];
    const float* w12 = (const float*)d_in[3];
    const float* w3  = (const float*)d_in[4];
    float* out = (float*)d_out;
    char* ws = (char*)d_ws;

    int*   ctrl       = (int*)(ws + OFF_CTRL);
    u16*   xb         = (u16*)(ws + OFF_XB);
    u16*   w12t       = (u16*)(ws + OFF_W12T);
    u16*   w3t        = (u16*)(ws + OFF_W3T);
    u16*   hidden     = (u16*)(ws + OFF_HID);
    float* ybuf       = (float*)(ws + OFF_Y);
    int*   pair_token = (int*)(ws + OFF_PTOK);
    int*   tok_expert = (int*)(ws + OFF_TE);
    float* tok_w      = (float*)(ws + OFF_TW);
    int*   tok_slot   = (int*)(ws + OFF_TS);

    hipMemsetAsync(ctrl, 0, 256, stream);
    hipMemsetAsync(out + (size_t)T_TOK * DIM, 0, sizeof(float), stream);  // aux slot

    router_kernel<<<T_TOK / 4, 256, 0, stream>>>(x, rw, rb, xb, tok_expert, tok_w, ctrl,
                                                 out + (size_t)T_TOK * DIM);
    transpose_cast_kernel<<<dim3(2 * HID / 32, DIM / 64, NE), 256, 0, stream>>>(w12, w12t, DIM, 2 * HID);
    transpose_cast_kernel<<<dim3(DIM / 32, HID / 64, NE), 256, 0, stream>>>(w3, w3t, HID, DIM);
    scan_kernel<<<1, 64, 0, stream>>>(ctrl);
    assign_kernel<<<16, 256, 0, stream>>>(tok_expert, tok_w, ctrl, pair_token, tok_slot);

    gemm1_kernel<<<dim3(HID / 64, 32, NE), 256, 0, stream>>>(xb, w12t, pair_token, ctrl, hidden);
    gemm2_kernel<<<dim3(DIM / 128, 32, NE), 256, 0, stream>>>(hidden, w3t, ctrl, ybuf);
    combine_kernel<<<T_TOK, 256, 0, stream>>>(ybuf, tok_slot, tok_w, out);
    (void)in_sizes; (void)n_in; (void)out_size; (void)ws_size;
}